// Round 8
// baseline (413.409 us; speedup 1.0000x reference)
//
#include <hip/hip_runtime.h>
#include <math.h>

#define TOKENS 16384
#define DD 4096
#define NE 64
#define MBLK 256      // tokens per k1 block
#define KB 16         // k-chunk

// async global->LDS, 16B per lane, LDS dest = uniform base + lane*16
#define GLDS16(gp, lp) __builtin_amdgcn_global_load_lds((gp), (lp), 16, 0, 0)

// ---- k0: transpose W[e][k] -> WT[k][e] (1 MB, once per launch) ----
__global__ void k0_transpose(const float* __restrict__ Wg, float* __restrict__ WT) {
  const int k0 = blockIdx.x * 64;
  const int e  = threadIdx.x & 63;
  const int kq = threadIdx.x >> 6;          // 0..3
#pragma unroll
  for (int kk = 0; kk < 16; ++kk) {
    const int k = k0 + kq * 16 + kk;
    WT[(long)k * NE + e] = Wg[(long)e * DD + k];
  }
}

// ---- k1: fp32 GEMM. Wave owns 16 experts (uniform); lane = 4 tokens. ----
// W LDS reads are wave-uniform (broadcast, free); x reads slot-swizzled.
__global__ __launch_bounds__(256, 2)
void k1_gemm(const float* __restrict__ x, const float* __restrict__ WT,
             float* __restrict__ part, int kPerSlice) {
  __shared__ __align__(16) float xs[2][MBLK * KB];  // 2 x 16 KB, [tok][16k] swizzled
  __shared__ __align__(16) float wt[2][KB * NE];    // 2 x 4 KB,  [kk][64e] linear

  const int nm   = TOKENS / MBLK;           // 64
  const int mblk = blockIdx.x % nm;
  const int s    = blockIdx.x / nm;
  const int tid  = threadIdx.x;
  const int lane = tid & 63;
  const int wid  = tid >> 6;
  const long t0  = (long)mblk * MBLK;
  const int k0   = s * kPerSlice;

  const int we0   = wid * 16;               // this wave's expert base (uniform)
  const int rdkey = (lane & 3) ^ ((lane >> 2) & 3);   // x slot swizzle key

  // x staging: wave stages tokens wid*64..+63 (4 GLDS rounds of 16 tokens)
  // granule (tok, slot=lane&3) holds kkc = slot ^ key(tok), key=(tok&3)^((tok>>2)&3)
  const int gkey = ((lane >> 2) & 3) ^ ((lane >> 4) & 3);
  const float* gxs[4];
#pragma unroll
  for (int q = 0; q < 4; ++q) {
    const int tok = wid * 64 + q * 16 + (lane >> 2);
    gxs[q] = x + (t0 + tok) * (long)DD + k0 + (((lane & 3) ^ gkey) << 2);
  }
  // W staging: linear 4KB chunk
  const float* gw = WT + (long)(k0 + wid * 4 + (lane >> 4)) * NE + (lane & 15) * 4;

  float acc[4][16];
#pragma unroll
  for (int i = 0; i < 4; ++i)
#pragma unroll
    for (int j = 0; j < 16; ++j) acc[i][j] = 0.f;

  const int nchunk = kPerSlice / KB;

  // prologue: stage chunk 0 -> buf 0
#pragma unroll
  for (int q = 0; q < 4; ++q) GLDS16(gxs[q], &xs[0][wid * 1024 + q * 256]);
  GLDS16(gw, &wt[0][wid * 256]);

  int cur = 0;
  for (int c = 0; c < nchunk; ++c) {
    __syncthreads();   // vmcnt(0) drain: buf cur ready

    if (c + 1 < nchunk) {                   // issue stage(c+1) -> other buf
      const int nb = cur ^ 1;
      const long go = (long)(c + 1) * KB;
#pragma unroll
      for (int q = 0; q < 4; ++q)
        GLDS16(gxs[q] + go, &xs[nb][wid * 1024 + q * 256]);
      GLDS16(gw + go * NE, &wt[nb][wid * 256]);
    }

    // compute chunk c (k ascending: kk = kkc*4+m)
#pragma unroll
    for (int kkc = 0; kkc < 4; ++kkc) {
      const int sl = (kkc ^ rdkey) << 2;
      float4 xv[4];
#pragma unroll
      for (int i = 0; i < 4; ++i)
        xv[i] = *(const float4*)&xs[cur][lane * 16 + i * 1024 + sl];
#pragma unroll
      for (int m = 0; m < 4; ++m) {
        const int kk = kkc * 4 + m;
        const float4 w0 = *(const float4*)&wt[cur][kk * NE + we0];      // uniform
        const float4 w1 = *(const float4*)&wt[cur][kk * NE + we0 + 4];  // -> broadcast
        const float4 w2 = *(const float4*)&wt[cur][kk * NE + we0 + 8];
        const float4 w3 = *(const float4*)&wt[cur][kk * NE + we0 + 12];
#pragma unroll
        for (int i = 0; i < 4; ++i) {
          const float xm = (&xv[i].x)[m];
          acc[i][0]  += xm * w0.x; acc[i][1]  += xm * w0.y;
          acc[i][2]  += xm * w0.z; acc[i][3]  += xm * w0.w;
          acc[i][4]  += xm * w1.x; acc[i][5]  += xm * w1.y;
          acc[i][6]  += xm * w1.z; acc[i][7]  += xm * w1.w;
          acc[i][8]  += xm * w2.x; acc[i][9]  += xm * w2.y;
          acc[i][10] += xm * w2.z; acc[i][11] += xm * w2.w;
          acc[i][12] += xm * w3.x; acc[i][13] += xm * w3.y;
          acc[i][14] += xm * w3.z; acc[i][15] += xm * w3.w;
        }
      }
    }
    cur ^= 1;
  }

  // store partials: lane's 4 tokens x this wave's 16 experts
  float* pb = part + ((long)s * TOKENS + t0 + lane) * NE + we0;
#pragma unroll
  for (int i = 0; i < 4; ++i) {
    float* pr = pb + (long)(64 * i) * NE;
    *(float4*)(pr)      = make_float4(acc[i][0],  acc[i][1],  acc[i][2],  acc[i][3]);
    *(float4*)(pr + 4)  = make_float4(acc[i][4],  acc[i][5],  acc[i][6],  acc[i][7]);
    *(float4*)(pr + 8)  = make_float4(acc[i][8],  acc[i][9],  acc[i][10], acc[i][11]);
    *(float4*)(pr + 12) = make_float4(acc[i][12], acc[i][13], acc[i][14], acc[i][15]);
  }
}

// ---- k2: reduce partials + softmax + top-2 + outputs ----
__global__ __launch_bounds__(256)
void k2_finish(const float* __restrict__ part, int S, float* __restrict__ out) {
  const int tid  = threadIdx.x;
  const int lane = tid & 63;
  const int wv   = tid >> 6;
  const long t   = (long)blockIdx.x * 4 + wv;

  const float* p = part + t * NE + lane;
  float logit = 0.f;
  for (int s = 0; s < S; ++s) logit += p[(long)s * TOKENS * NE];

  out[4 * TOKENS + t * NE + lane] = logit;  // logits region

  // argmax (tie -> lowest index, matches jax.lax.top_k)
  float v = logit; int i = lane;
#pragma unroll
  for (int off = 32; off; off >>= 1) {
    float ov = __shfl_xor(v, off);
    int   oi = __shfl_xor(i, off);
    if (ov > v || (ov == v && oi < i)) { v = ov; i = oi; }
  }
  const float m = v; const int i1 = i;

  float vv = (lane == i1) ? -INFINITY : logit; int ii = lane;
#pragma unroll
  for (int off = 32; off; off >>= 1) {
    float ov = __shfl_xor(vv, off);
    int   oi = __shfl_xor(ii, off);
    if (ov > vv || (ov == vv && oi < ii)) { vv = ov; ii = oi; }
  }
  const int i2 = ii;

  float z = expf(logit - m);
  float Z = z;
#pragma unroll
  for (int off = 32; off; off >>= 1) Z += __shfl_xor(Z, off);

  float p1 = __shfl(z, i1) / Z;
  float p2 = __shfl(z, i2) / Z;

  if (lane == 0) {
    float denom = p1 + p2 + 1e-9f;
    out[t * 2 + 0] = (float)i1;               // indices [0, 2T)
    out[t * 2 + 1] = (float)i2;
    out[2 * TOKENS + t * 2 + 0] = p1 / denom; // weights [2T, 4T)
    out[2 * TOKENS + t * 2 + 1] = p2 / denom;
  }
}

extern "C" void kernel_launch(void* const* d_in, const int* in_sizes, int n_in,
                              void* d_out, int out_size, void* d_ws, size_t ws_size,
                              hipStream_t stream) {
  const float* x  = (const float*)d_in[0];
  const float* Wg = (const float*)d_in[1];
  float* out = (float*)d_out;

  float* WT = (float*)d_ws;
  const size_t wtBytes    = (size_t)DD * NE * sizeof(float);      // 1 MB
  const size_t sliceBytes = (size_t)TOKENS * NE * sizeof(float);  // 4.19 MB

  int S = 8;
  while (S > 1 && wtBytes + (size_t)S * sliceBytes > ws_size) S >>= 1;
  float* part = (float*)((char*)d_ws + wtBytes);
  if (wtBytes + sliceBytes > ws_size) {      // degenerate tiny-ws fallback
    S = 1;
    part = out + 4 * TOKENS;                 // logits region doubles as partials
  }
  const int kPerSlice = DD / S;              // divisible by KB for S in {1..8}

  k0_transpose<<<dim3(DD / 64), 256, 0, stream>>>(Wg, WT);
  k1_gemm<<<dim3((TOKENS / MBLK) * S), 256, 0, stream>>>(x, WT, part, kPerSlice);
  k2_finish<<<dim3(TOKENS / 4), 256, 0, stream>>>(part, S, out);
}